// Round 2
// baseline (634.662 us; speedup 1.0000x reference)
//
#include <hip/hip_runtime.h>
#include <math.h>

// ---------------------------------------------------------------------------
// HierarchicalVQEncoder forward.
//
// Eval mode: assign = hard one-hot (soft terms cancel), so out[b,t] depends
// ONLY on (idx1[b], idx2[b,t]) -> 8*32=256-row table + gather.
//
// idx2 = argmax_k [ r . H_b[:,k] + f_b[k] ],  r = relu(ln(x@Wl1^T+bl1))
// (argmax invariant to LN/l2norm positive scaling; H,f fold Wl2,Wtb,btb,cb2.)
//
// Precision: big GEMM fp32 (matches reference's own rounding regime),
// all cheap folding math fp64.
// ---------------------------------------------------------------------------

#define TM 32
#define KB 32

typedef __attribute__((address_space(3))) void lds_void_t;
typedef const __attribute__((address_space(1))) void glb_void_t;

__device__ __forceinline__ void async_copy16(const float* g, float* l){
  __builtin_amdgcn_global_load_lds((glb_void_t*)g, (lds_void_t*)l, 16, 0, 0);
}

__device__ __forceinline__ double blk_sum_256(double v, double* red){
  const int tid = threadIdx.x;
  red[tid] = v; __syncthreads();
  #pragma unroll
  for(int s=128; s>0; s>>=1){ if(tid < s) red[tid] += red[tid+s]; __syncthreads(); }
  const double r = red[0]; __syncthreads();
  return r;
}

// ---- P1: partial sums for mean/std over T -------------------------------
__global__ __launch_bounds__(256) void hvq_p1_partial(
    const float* __restrict__ x, double* __restrict__ psum, double* __restrict__ psumsq){
  const int tc = blockIdx.x;          // 0..15, 128 t each
  const int b  = blockIdx.y;          // 0..15
  const int d4 = threadIdx.x * 4;
  const float* xp = x + ((size_t)(b*2048 + tc*128))*1024 + d4;
  double s0=0,s1=0,s2=0,s3=0, q0=0,q1=0,q2=0,q3=0;
  for(int t=0;t<128;t++){
    const float4 v = *(const float4*)&xp[(size_t)t*1024];
    s0 += v.x; q0 += (double)v.x*v.x;
    s1 += v.y; q1 += (double)v.y*v.y;
    s2 += v.z; q2 += (double)v.z*v.z;
    s3 += v.w; q3 += (double)v.w*v.w;
  }
  const size_t o = ((size_t)(b*16+tc))*1024 + d4;
  psum[o+0]=s0; psum[o+1]=s1; psum[o+2]=s2; psum[o+3]=s3;
  psumsq[o+0]=q0; psumsq[o+1]=q1; psumsq[o+2]=q2; psumsq[o+3]=q3;
}

// ---- P2 (fused p1_final): stats -> global encoder -> idx1, cbn ----------
__global__ __launch_bounds__(256) void hvq_p2(
    const double* __restrict__ psum, const double* __restrict__ psumsq,
    const float* __restrict__ Wg1, const float* __restrict__ bg1,
    const float* __restrict__ Wg2, const float* __restrict__ bg2,
    const float* __restrict__ Wp,  const float* __restrict__ bp,
    const float* __restrict__ cb1, const float* __restrict__ cb2,
    int* __restrict__ idx1_g, float* __restrict__ cbn){
  __shared__ float gin[1024];
  __shared__ float sa[256];
  __shared__ float sb[128];
  __shared__ float sh[128];
  __shared__ double red[256];
  __shared__ double lg[8];
  __shared__ double nrm[32];
  __shared__ int i1s;
  const int b = blockIdx.x, tid = threadIdx.x;

  // fused p1_final: g_in = mean + std (ddof=1)
  for(int i=tid;i<1024;i+=256){
    double s=0, ss=0;
    for(int tc=0;tc<16;tc++){
      const size_t o = ((size_t)(b*16+tc))*1024 + i;
      s += psum[o]; ss += psumsq[o];
    }
    const double mean = s / 2048.0;
    double var = (ss - s*mean) / 2047.0;
    if(var < 0) var = 0;
    gin[i] = (float)(mean + sqrt(var));
  }
  __syncthreads();

  // z = g_in @ Wg1^T + bg1   (fp64 acc)
  double z = 0;
  {
    const float* wr = Wg1 + (size_t)tid*1024;
    for(int d=0; d<1024; d+=4){
      const float4 w = *(const float4*)&wr[d];
      z += (double)gin[d]*w.x + (double)gin[d+1]*w.y
         + (double)gin[d+2]*w.z + (double)gin[d+3]*w.w;
    }
    z += (double)bg1[tid];
  }
  const double mz = blk_sum_256(z, red) / 256.0;
  const double dz = z - mz;
  const double vz = blk_sum_256(dz*dz, red) / 256.0;
  double a = dz / sqrt(vz + 1e-5);
  if(a < 0) a = 0;
  sa[tid] = (float)a;
  __syncthreads();

  if(tid < 128){
    const float* wr = Wg2 + (size_t)tid*256;
    double g = 0;
    for(int i=0;i<256;i++) g += (double)sa[i]*(double)wr[i];
    sb[tid] = (float)(g + (double)bg2[tid]);
  }
  __syncthreads();

  double h = 0;
  if(tid < 128){
    const float* wr = Wp + (size_t)tid*128;
    for(int i=0;i<128;i++) h += (double)sb[i]*(double)wr[i];
    h += (double)bp[tid];
  }
  const double mh = blk_sum_256(tid<128 ? h : 0.0, red) / 128.0;
  const double dh = (tid<128) ? (h - mh) : 0.0;
  const double vh = blk_sum_256(dh*dh, red) / 128.0;
  const double h1 = dh / sqrt(vh + 1e-5);
  if(tid < 128) sh[tid] = (float)h1;
  const double nh2 = blk_sum_256(tid<128 ? h1*h1 : 0.0, red);
  const double normh = sqrt(nh2);
  __syncthreads();

  if(tid < 8){
    const float* cr = cb1 + tid*128;
    double dsum=0, n2=0;
    for(int i=0;i<128;i++){ const double c=(double)cr[i]; dsum += (double)sh[i]*c; n2 += c*c; }
    lg[tid] = dsum / (fmax(normh,1e-12) * fmax(sqrt(n2),1e-12));
  }
  __syncthreads();
  if(tid == 0){
    int bi=0; double bv=lg[0];
    for(int j=1;j<8;j++) if(lg[j] > bv){ bv=lg[j]; bi=j; }
    i1s = bi; idx1_g[b] = bi;
  }
  __syncthreads();
  const int i1 = i1s;
  if(tid < 32){
    const float* cr = cb2 + ((size_t)i1*32 + tid)*64;
    double n2=0;
    for(int c=0;c<64;c++){ const double v=(double)cr[c]; n2 += v*v; }
    nrm[tid] = fmax(sqrt(n2), 1e-12);
  }
  __syncthreads();
  for(int i=tid;i<2048;i+=256){
    const int kk = i >> 6, c = i & 63;
    cbn[(size_t)b*2048 + i] = (float)((double)cb2[((size_t)i1*32+kk)*64 + c] / nrm[kk]);
  }
}

// ---- P3a: transpose Wl1 (256,1024) -> Wl1T (1024,256) -------------------
__global__ __launch_bounds__(256) void hvq_p3a(
    const float* __restrict__ Wl1, float* __restrict__ Wl1T){
  const int o = blockIdx.x*1024 + threadIdx.x*4;
  const int k = o >> 8;
  const int n = o & 255;
  float4 v;
  v.x = Wl1[(size_t)(n+0)*1024 + k];
  v.y = Wl1[(size_t)(n+1)*1024 + k];
  v.z = Wl1[(size_t)(n+2)*1024 + k];
  v.w = Wl1[(size_t)(n+3)*1024 + k];
  *(float4*)&Wl1T[o] = v;
}

// ---- P3c (fused p3b): per-(ng,b) fold H[b][n][k], f[b][k] ---------------
__global__ __launch_bounds__(256) void hvq_p3c(
    const float* __restrict__ Wtb, const float* __restrict__ Wl2,
    const float* __restrict__ bl2, const float* __restrict__ btb,
    const float* __restrict__ cbn, float* __restrict__ H, float* __restrict__ f){
  const int ng = blockIdx.x;           // 0..7 (32 n each)
  const int b  = blockIdx.y;           // 0..15
  const int tn = threadIdx.x & 31;
  const int kq = threadIdx.x >> 5;     // 0..7
  const int n  = ng*32 + tn;
  __shared__ double Wcs[64][33];       // [c][n-in-group], padded
  __shared__ double bcs[64];

  // Wc slice: Wc[c][n] = sum_j Wtb[c][j]*Wl2[j][n], c = kq*8..+7  (fp64)
  {
    double acc[8] = {0,0,0,0,0,0,0,0};
    const float* wt = Wtb + (size_t)(kq*8)*256;
    for(int j=0;j<256;j++){
      const double wl = (double)Wl2[(size_t)j*256 + n];
      #pragma unroll
      for(int cc=0;cc<8;cc++) acc[cc] += (double)wt[cc*256 + j] * wl;
    }
    #pragma unroll
    for(int cc=0;cc<8;cc++) Wcs[kq*8+cc][tn] = acc[cc];
  }
  // bc[c] = Wtb[c]@bl2 + btb[c]
  if(threadIdx.x < 64){
    const int c = threadIdx.x;
    const float* wt = Wtb + (size_t)c*256;
    double a = 0;
    for(int j=0;j<256;j++) a += (double)wt[j]*(double)bl2[j];
    bcs[c] = a + (double)btb[c];
  }
  __syncthreads();

  double su = 0;
  for(int c=0;c<64;c++) su += Wcs[c][tn];
  su /= 64.0;
  for(int t=0;t<4;t++){
    const int k = kq*4 + t;
    const float* cb = cbn + ((size_t)b*32 + k)*64;
    double acc=0, sk=0;
    for(int c=0;c<64;c++){ const double cc=(double)cb[c]; acc += Wcs[c][tn]*cc; sk += cc; }
    H[((size_t)b*256 + n)*32 + k] = (float)(acc - su*sk);
  }
  if(ng == 0 && threadIdx.x < 32){
    const int k = threadIdx.x;
    const float* cb = cbn + ((size_t)b*32 + k)*64;
    double acc=0, sk=0, sbc=0;
    for(int c=0;c<64;c++){ const double cc=(double)cb[c]; acc += bcs[c]*cc; sk += cc; sbc += bcs[c]; }
    f[b*32 + k] = (float)(acc - (sbc/64.0)*sk);
  }
}

// ---- P4: output table (256 rows x 256) ----------------------------------
__global__ __launch_bounds__(256) void hvq_p4(
    const float* __restrict__ cb2, const float* __restrict__ cb1,
    const float* __restrict__ Wfb, const float* __restrict__ bfb,
    const float* __restrict__ Wf,  const float* __restrict__ bf,
    float* __restrict__ table){
  const int i1 = blockIdx.x >> 5, k2 = blockIdx.x & 31;
  __shared__ float e[64];
  __shared__ float fused[384];
  __shared__ double red[256];
  const int j = threadIdx.x;
  if(j < 64) e[j] = cb2[((size_t)i1*32 + k2)*64 + j];
  if(j >= 128) fused[256 + (j-128)] = cb1[i1*128 + (j-128)];
  __syncthreads();

  double t = 0;
  {
    const float* wr = Wfb + (size_t)j*64;
    for(int c=0;c<64;c++) t += (double)e[c]*(double)wr[c];
    t += (double)bfb[j];
  }
  double m = blk_sum_256(t, red) / 256.0;
  double d = t - m;
  double v = blk_sum_256(d*d, red) / 256.0;
  fused[j] = (float)(d / sqrt(v + 1e-5));
  __syncthreads();

  double o = 0;
  {
    const float* wr = Wf + (size_t)j*384;
    for(int i=0;i<384;i++) o += (double)fused[i]*(double)wr[i];
    o += (double)bf[j];
  }
  m = blk_sum_256(o, red) / 256.0;
  d = o - m;
  v = blk_sum_256(d*d, red) / 256.0;
  double r = d / sqrt(v + 1e-5);
  if(r < 0) r = 0;
  table[(size_t)blockIdx.x*256 + j] = (float)r;
}

// ---- Main: GEMM (x@Wl1^T) + LN + ReLU + scores + argmax + gather --------
// Staging via global_load_lds DMA (16B/lane, wave-uniform LDS base).
__global__ __launch_bounds__(256) void hvq_main(
    const float* __restrict__ x, const float* __restrict__ Wl1T,
    const float* __restrict__ bl1, const float* __restrict__ H,
    const float* __restrict__ f, const int* __restrict__ idx1,
    const float* __restrict__ table, float* __restrict__ out){
  __shared__ float wsT[KB*256];   // [kk][n] 32KB; aliased as rT[256][32] after K-loop
  __shared__ float xs[TM*KB];     // [m][kk] 4KB
  __shared__ int kstar[TM];

  const int tid = threadIdx.x;
  const int tx = tid & 31, ty = tid >> 5;
  const int wave = tid >> 6;      // 0..3
  const int lane = tid & 63;
  const int b  = blockIdx.y;
  const int t0 = blockIdx.x * TM;
  const float* xbase = x + ((size_t)(b*2048 + t0))*1024;

  float acc[4][8];
  #pragma unroll
  for(int j=0;j<4;j++)
    #pragma unroll
    for(int c=0;c<8;c++) acc[j][c] = 0.f;

  float bn[8];
  #pragma unroll
  for(int c=0;c<4;c++){ bn[c] = bl1[tx*4+c]; bn[c+4] = bl1[128 + tx*4 + c]; }

  // DMA source/dest precompute.
  // W: wave handles floats [wave*2048, +2048) of the 32KB tile (8 insts x 1KB)
  // x: wave handles rows 8w..8w+7; lane -> (row = 8w + lane/8, 16B chunk lane%8)
  const float* xsrc0 = x + ((size_t)(b*2048 + t0 + 8*wave + (lane>>3)))*1024 + (lane&7)*4;
  float* xdst = xs + wave*256;                 // + lane*4 implicit (lane x 16B)
  float* wdst = wsT + wave*2048;               // + lane*4 implicit per inst

  for(int kt=0; kt<1024/KB; kt++){
    const int k0 = kt*KB;
    const float* wsrc = Wl1T + (size_t)k0*256 + wave*2048 + lane*4;
    #pragma unroll
    for(int i=0;i<8;i++) async_copy16(wsrc + i*256, wdst + i*256);
    async_copy16(xsrc0 + k0, xdst);
    __syncthreads();

    #pragma unroll 8
    for(int kk=0;kk<KB;kk++){
      const float4 w0 = *(const float4*)&wsT[kk*256 + tx*4];
      const float4 w1 = *(const float4*)&wsT[kk*256 + 128 + tx*4];
      #pragma unroll
      for(int j=0;j<4;j++){
        const float xv = xs[(ty*4+j)*KB + kk];
        acc[j][0] = fmaf(xv, w0.x, acc[j][0]);
        acc[j][1] = fmaf(xv, w0.y, acc[j][1]);
        acc[j][2] = fmaf(xv, w0.z, acc[j][2]);
        acc[j][3] = fmaf(xv, w0.w, acc[j][3]);
        acc[j][4] = fmaf(xv, w1.x, acc[j][4]);
        acc[j][5] = fmaf(xv, w1.y, acc[j][5]);
        acc[j][6] = fmaf(xv, w1.z, acc[j][6]);
        acc[j][7] = fmaf(xv, w1.w, acc[j][7]);
      }
    }
    __syncthreads();
  }

  // bias + LN(256) over row (reduce across 32 tx lanes) + ReLU -> rT
  float* rT = wsT;    // [n][m] = [256][32]
  #pragma unroll
  for(int j=0;j<4;j++){
    float s = 0.f;
    #pragma unroll
    for(int c=0;c<8;c++){ acc[j][c] += bn[c]; s += acc[j][c]; }
    #pragma unroll
    for(int off=16;off>=1;off>>=1) s += __shfl_xor(s, off);
    const float mean = s * (1.f/256.f);
    float d2 = 0.f;
    #pragma unroll
    for(int c=0;c<8;c++){ const float dv = acc[j][c]-mean; d2 += dv*dv; }
    #pragma unroll
    for(int off=16;off>=1;off>>=1) d2 += __shfl_xor(d2, off);
    const float inv = 1.f / sqrtf(d2*(1.f/256.f) + 1e-5f);
    const int m = ty*4 + j;
    #pragma unroll
    for(int c=0;c<8;c++){
      float r = (acc[j][c]-mean)*inv;
      r = fmaxf(r, 0.f);
      const int n = (c < 4) ? (tx*4 + c) : (128 + tx*4 + (c-4));
      rT[n*TM + m] = r;
    }
  }
  __syncthreads();

  // scores[m][k] = f_k + sum_n r[m][n]*H[b][n][k]; argmax over k (32 lanes)
  const int k = tid & 31, mg = tid >> 5;
  const float* Hb = H + (size_t)b*256*32 + k;
  const float fk = f[b*32 + k];
  float s0=fk, s1=fk, s2=fk, s3=fk;
  #pragma unroll 4
  for(int n=0;n<256;n++){
    const float4 rm = *(const float4*)&rT[n*TM + mg*4];
    const float hv = Hb[(size_t)n*32];
    s0 = fmaf(rm.x, hv, s0);
    s1 = fmaf(rm.y, hv, s1);
    s2 = fmaf(rm.z, hv, s2);
    s3 = fmaf(rm.w, hv, s3);
  }
  float scv[4] = {s0, s1, s2, s3};
  #pragma unroll
  for(int j=0;j<4;j++){
    float best = scv[j]; int bi = k;
    #pragma unroll
    for(int off=16;off>=1;off>>=1){
      const float ov = __shfl_xor(best, off);
      const int   oi = __shfl_xor(bi, off);
      if(ov > best || (ov == best && oi < bi)){ best = ov; bi = oi; }
    }
    if(k == 0) kstar[mg*4 + j] = bi;
  }
  __syncthreads();

  const int i1 = idx1[b];
  float* ob = out + ((size_t)(b*2048 + t0))*256;
  for(int m=0;m<TM;m++){
    const float v = table[((size_t)(i1*32 + kstar[m]))*256 + tid];
    ob[(size_t)m*256 + tid] = v;
  }
}

// ---------------------------------------------------------------------------
extern "C" void kernel_launch(void* const* d_in, const int* in_sizes, int n_in,
                              void* d_out, int out_size, void* d_ws, size_t ws_size,
                              hipStream_t stream){
  const float* x   = (const float*)d_in[0];
  const float* Wg1 = (const float*)d_in[1];
  const float* bg1 = (const float*)d_in[2];
  const float* Wg2 = (const float*)d_in[3];
  const float* bg2 = (const float*)d_in[4];
  const float* Wl1 = (const float*)d_in[5];
  const float* bl1 = (const float*)d_in[6];
  const float* Wl2 = (const float*)d_in[7];
  const float* bl2 = (const float*)d_in[8];
  const float* Wp  = (const float*)d_in[9];
  const float* bp  = (const float*)d_in[10];
  const float* cb1 = (const float*)d_in[11];
  const float* Wtb = (const float*)d_in[12];
  const float* btb = (const float*)d_in[13];
  const float* Wfb = (const float*)d_in[14];
  const float* bfb = (const float*)d_in[15];
  const float* cb2 = (const float*)d_in[16];
  const float* Wf  = (const float*)d_in[17];
  const float* bf  = (const float*)d_in[18];
  float* out = (float*)d_out;

  char* w = (char*)d_ws;
  double* psum   = (double*)w; w += (size_t)16*16*1024*8;   // 2 MB
  double* psumsq = (double*)w; w += (size_t)16*16*1024*8;   // 2 MB
  float*  cbn    = (float*)w;  w += (size_t)16*32*64*4;
  int*    idx1   = (int*)w;    w += 64;
  float*  Wl1T   = (float*)w;  w += (size_t)1024*256*4;     // 1 MB
  float*  Hq     = (float*)w;  w += (size_t)16*256*32*4;    // 512 KB
  float*  fq     = (float*)w;  w += (size_t)16*32*4;
  float*  table  = (float*)w;  w += (size_t)256*256*4;      // 256 KB

  hvq_p1_partial<<<dim3(16,16), 256, 0, stream>>>(x, psum, psumsq);
  hvq_p3a<<<256, 256, 0, stream>>>(Wl1, Wl1T);
  hvq_p4<<<256, 256, 0, stream>>>(cb2, cb1, Wfb, bfb, Wf, bf, table);
  hvq_p2<<<16, 256, 0, stream>>>(psum, psumsq, Wg1, bg1, Wg2, bg2, Wp, bp, cb1, cb2, idx1, cbn);
  hvq_p3c<<<dim3(8,16), 256, 0, stream>>>(Wtb, Wl2, bl2, btb, cbn, Hq, fq);
  hvq_main<<<dim3(64,16), 256, 0, stream>>>(x, Wl1T, bl1, Hq, fq, idx1, table, out);
}

// Round 3
// 614.214 us; speedup vs baseline: 1.0333x; 1.0333x over previous
//
#include <hip/hip_runtime.h>
#include <math.h>

// ---------------------------------------------------------------------------
// HierarchicalVQEncoder forward.
//
// Eval mode: assign = hard one-hot (soft terms cancel), so out[b,t] depends
// ONLY on (idx1[b], idx2[b,t]) -> 8*32=256-row table + gather.
//
// idx2 = argmax_k [ r . H_all[i1][:,k] + f_all[i1][k] ],
//   r = relu(ln(x@Wl1^T+bl1))   (argmax invariant to positive scaling;
//   H,f fold Wl2,Wtb,btb,cb2; computed for ALL 8 i1 to break dependency)
//
// 3-kernel DAG:
//   A: x partial stats | tiled transposes (Wl1,Wg1,Wg2,Wp,Wf,Wfb) | fold H_all
//   B: global encoder -> idx1 (16 blocks) | output table (256 blocks)
//   C: main GEMM + LN + scores + argmax + table gather
//
// Precision: big GEMM fp32, all folding math fp64.
// ---------------------------------------------------------------------------

#define TM 32
#define KB 32

typedef __attribute__((address_space(3))) void lds_void_t;
typedef const __attribute__((address_space(1))) void glb_void_t;

__device__ __forceinline__ void async_copy16(const float* g, float* l){
  __builtin_amdgcn_global_load_lds((glb_void_t*)g, (lds_void_t*)l, 16, 0, 0);
}

__device__ __forceinline__ double blk_sum_256(double v, double* red){
  const int tid = threadIdx.x;
  red[tid] = v; __syncthreads();
  #pragma unroll
  for(int s=128; s>0; s>>=1){ if(tid < s) red[tid] += red[tid+s]; __syncthreads(); }
  const double r = red[0]; __syncthreads();
  return r;
}

// ---- tiled 64x64 transpose helper (coalesced in AND out) ----------------
__device__ __forceinline__ void tile_transpose(
    const float* __restrict__ src, float* __restrict__ dst,
    int M, int N, int tile_id, float (*tile)[65]){
  const int tpr = N >> 6;
  const int r0 = (tile_id / tpr) << 6;
  const int c0 = (tile_id % tpr) << 6;
  const int t = threadIdx.x;
  {
    const int i = t >> 4, j4 = (t & 15) << 2;
    #pragma unroll
    for(int q=0;q<4;q++){
      const int row = i + (q<<4);
      const float4 v = *(const float4*)&src[(size_t)(r0+row)*N + c0 + j4];
      tile[row][j4+0]=v.x; tile[row][j4+1]=v.y; tile[row][j4+2]=v.z; tile[row][j4+3]=v.w;
    }
  }
  __syncthreads();
  {
    const int j = t >> 4, i4 = (t & 15) << 2;
    #pragma unroll
    for(int q=0;q<4;q++){
      const int col = j + (q<<4);
      float4 o;
      o.x = tile[i4+0][col]; o.y = tile[i4+1][col];
      o.z = tile[i4+2][col]; o.w = tile[i4+3][col];
      *(float4*)&dst[(size_t)(c0+col)*M + r0 + i4] = o;
    }
  }
}

// ========================= Kernel A (488 blocks) =========================
// [0,256)   p1 partial sums over T
// [256,320) Wl1 -> Wl1T (1024x256)
// [320,384) Wg1 -> Wg1T (1024x256)
// [384,408) Wf  -> WfT  (384x256)
// [408,412) Wfb -> WfbT (64x256)
// [412,420) Wg2 -> Wg2T (256x128)
// [420,424) Wp  -> WpT  (128x128)
// [424,488) fold H_all[8][256][32], f_all[8][32]
union SmemA {
  float tile[64][65];
  struct { double Wcs[64][33]; double bcs[64]; double cbd[32][64]; double nrm[32]; } fold;
};

__global__ __launch_bounds__(256) void hvq_A(
    const float* __restrict__ x,
    const float* __restrict__ Wl1, const float* __restrict__ Wg1,
    const float* __restrict__ Wf,  const float* __restrict__ Wfb,
    const float* __restrict__ Wg2, const float* __restrict__ Wp,
    const float* __restrict__ Wtb, const float* __restrict__ Wl2,
    const float* __restrict__ bl2, const float* __restrict__ btb,
    const float* __restrict__ cb2,
    double* __restrict__ psum, double* __restrict__ psumsq,
    float* __restrict__ Wl1T, float* __restrict__ Wg1T,
    float* __restrict__ WfT,  float* __restrict__ WfbT,
    float* __restrict__ Wg2T, float* __restrict__ WpT,
    float* __restrict__ H_all, float* __restrict__ f_all){
  __shared__ SmemA sm;
  const int blk = blockIdx.x;
  const int tid = threadIdx.x;

  if(blk < 256){
    // ---- p1 partial: per (b, t-chunk) sums/sumsq over 128 t ----
    const int tc = blk & 15, b = blk >> 4;
    const int d4 = tid * 4;
    const float* xp = x + ((size_t)(b*2048 + tc*128))*1024 + d4;
    double s0=0,s1=0,s2=0,s3=0, q0=0,q1=0,q2=0,q3=0;
    for(int t=0;t<128;t++){
      const float4 v = *(const float4*)&xp[(size_t)t*1024];
      s0 += v.x; q0 += (double)v.x*v.x;
      s1 += v.y; q1 += (double)v.y*v.y;
      s2 += v.z; q2 += (double)v.z*v.z;
      s3 += v.w; q3 += (double)v.w*v.w;
    }
    const size_t o = ((size_t)(b*16+tc))*1024 + d4;
    psum[o+0]=s0; psum[o+1]=s1; psum[o+2]=s2; psum[o+3]=s3;
    psumsq[o+0]=q0; psumsq[o+1]=q1; psumsq[o+2]=q2; psumsq[o+3]=q3;
  } else if(blk < 320){
    tile_transpose(Wl1, Wl1T, 256, 1024, blk-256, sm.tile);
  } else if(blk < 384){
    tile_transpose(Wg1, Wg1T, 256, 1024, blk-320, sm.tile);
  } else if(blk < 408){
    tile_transpose(Wf,  WfT,  256, 384,  blk-384, sm.tile);
  } else if(blk < 412){
    tile_transpose(Wfb, WfbT, 256, 64,   blk-408, sm.tile);
  } else if(blk < 420){
    tile_transpose(Wg2, Wg2T, 128, 256,  blk-412, sm.tile);
  } else if(blk < 424){
    tile_transpose(Wp,  WpT,  128, 128,  blk-420, sm.tile);
  } else {
    // ---- fold: H_all[i1][n][k], f_all[i1][k] (fp64) ----
    const int fb = blk - 424;
    const int ng = fb & 7;          // n-group (32 n each)
    const int i1 = fb >> 3;         // 0..7
    const int tn = tid & 31;
    const int kq = tid >> 5;        // 0..7
    const int n  = ng*32 + tn;

    if(tid < 32){
      const float* cr = cb2 + ((size_t)i1*32 + tid)*64;
      double n2 = 0;
      for(int c=0;c<64;c++){ const double v=(double)cr[c]; n2 += v*v; }
      sm.fold.nrm[tid] = fmax(sqrt(n2), 1e-12);
    }
    __syncthreads();
    for(int i=tid;i<2048;i+=256){
      const int k = i >> 6, c = i & 63;
      sm.fold.cbd[k][c] = (double)cb2[((size_t)i1*32+k)*64 + c] / sm.fold.nrm[k];
    }
    // Wc slice: Wc[c][n] = sum_j Wtb[c][j]*Wl2[j][n], c = kq*8..+7
    {
      double acc[8] = {0,0,0,0,0,0,0,0};
      const float* wt = Wtb + (size_t)(kq*8)*256;
      for(int j=0;j<256;j++){
        const double wl = (double)Wl2[(size_t)j*256 + n];   // coalesced across tn
        #pragma unroll
        for(int cc=0;cc<8;cc++) acc[cc] += (double)wt[cc*256 + j] * wl;
      }
      #pragma unroll
      for(int cc=0;cc<8;cc++) sm.fold.Wcs[kq*8+cc][tn] = acc[cc];
    }
    if(tid < 64){
      const float* wt = Wtb + (size_t)tid*256;
      double a = 0;
      for(int j=0;j<256;j++) a += (double)wt[j]*(double)bl2[j];
      sm.fold.bcs[tid] = a + (double)btb[tid];
    }
    __syncthreads();

    double su = 0;
    for(int c=0;c<64;c++) su += sm.fold.Wcs[c][tn];
    su /= 64.0;
    for(int t=0;t<4;t++){
      const int k = kq*4 + t;
      double acc=0, sk=0;
      for(int c=0;c<64;c++){ const double cc = sm.fold.cbd[k][c]; acc += sm.fold.Wcs[c][tn]*cc; sk += cc; }
      H_all[((size_t)i1*256 + n)*32 + k] = (float)(acc - su*sk);
    }
    if(ng == 0 && tid < 32){
      const int k = tid;
      double acc=0, sk=0, sbc=0;
      for(int c=0;c<64;c++){ const double cc = sm.fold.cbd[k][c]; acc += sm.fold.bcs[c]*cc; sk += cc; sbc += sm.fold.bcs[c]; }
      f_all[i1*32 + k] = (float)(acc - (sbc/64.0)*sk);
    }
  }
}

// ========================= Kernel B (272 blocks) =========================
// [0,16)   p2: stats final + global encoder -> idx1[b]
// [16,272) p4: output table row (i1,k2)
union SmemB {
  struct { float gin[1024]; float sa[256]; float sb[128]; float sh[128];
           double red[256]; double lg[8]; int i1s; } p2;
  struct { float e[64]; float fused[384]; double red[256]; } p4;
};

__global__ __launch_bounds__(256) void hvq_B(
    const double* __restrict__ psum, const double* __restrict__ psumsq,
    const float* __restrict__ Wg1T, const float* __restrict__ bg1,
    const float* __restrict__ Wg2T, const float* __restrict__ bg2,
    const float* __restrict__ WpT,  const float* __restrict__ bp,
    const float* __restrict__ cb1,  const float* __restrict__ cb2,
    const float* __restrict__ WfbT, const float* __restrict__ bfb,
    const float* __restrict__ WfT,  const float* __restrict__ bf,
    int* __restrict__ idx1_g, float* __restrict__ table){
  __shared__ SmemB sm;
  const int tid = threadIdx.x;

  if(blockIdx.x < 16){
    const int b = blockIdx.x;
    // g_in = mean + std (ddof=1), fp64
    for(int i=tid;i<1024;i+=256){
      double s=0, ss=0;
      for(int tc=0;tc<16;tc++){
        const size_t o = ((size_t)(b*16+tc))*1024 + i;
        s += psum[o]; ss += psumsq[o];
      }
      const double mean = s / 2048.0;
      double var = (ss - s*mean) / 2047.0;
      if(var < 0) var = 0;
      sm.p2.gin[i] = (float)(mean + sqrt(var));
    }
    __syncthreads();

    // z = g_in @ Wg1^T + bg1  (coalesced via Wg1T)
    double z = 0;
    {
      #pragma unroll 8
      for(int k=0;k<1024;k++) z += (double)sm.p2.gin[k] * (double)Wg1T[(size_t)k*256 + tid];
      z += (double)bg1[tid];
    }
    const double mz = blk_sum_256(z, sm.p2.red) / 256.0;
    const double dz = z - mz;
    const double vz = blk_sum_256(dz*dz, sm.p2.red) / 256.0;
    double a = dz / sqrt(vz + 1e-5);
    if(a < 0) a = 0;
    sm.p2.sa[tid] = (float)a;
    __syncthreads();

    if(tid < 128){
      double g = 0;
      #pragma unroll 8
      for(int i=0;i<256;i++) g += (double)sm.p2.sa[i]*(double)Wg2T[(size_t)i*128 + tid];
      sm.p2.sb[tid] = (float)(g + (double)bg2[tid]);
    }
    __syncthreads();

    double h = 0;
    if(tid < 128){
      #pragma unroll 8
      for(int i=0;i<128;i++) h += (double)sm.p2.sb[i]*(double)WpT[(size_t)i*128 + tid];
      h += (double)bp[tid];
    }
    const double mh = blk_sum_256(tid<128 ? h : 0.0, sm.p2.red) / 128.0;
    const double dh = (tid<128) ? (h - mh) : 0.0;
    const double vh = blk_sum_256(dh*dh, sm.p2.red) / 128.0;
    const double h1 = dh / sqrt(vh + 1e-5);
    if(tid < 128) sm.p2.sh[tid] = (float)h1;
    const double nh2 = blk_sum_256(tid<128 ? h1*h1 : 0.0, sm.p2.red);
    const double normh = sqrt(nh2);
    __syncthreads();

    if(tid < 8){
      const float* cr = cb1 + tid*128;
      double dsum=0, n2=0;
      for(int i=0;i<128;i++){ const double c=(double)cr[i]; dsum += (double)sm.p2.sh[i]*c; n2 += c*c; }
      sm.p2.lg[tid] = dsum / (fmax(normh,1e-12) * fmax(sqrt(n2),1e-12));
    }
    __syncthreads();
    if(tid == 0){
      int bi=0; double bv=sm.p2.lg[0];
      for(int j=1;j<8;j++) if(sm.p2.lg[j] > bv){ bv=sm.p2.lg[j]; bi=j; }
      idx1_g[b] = bi;
    }
  } else {
    // ---- p4: table row for (i1,k2) ----
    const int row = blockIdx.x - 16;
    const int i1 = row >> 5, k2 = row & 31;
    const int j = tid;
    if(j < 64) sm.p4.e[j] = cb2[((size_t)i1*32 + k2)*64 + j];
    if(j >= 128 && j < 256) sm.p4.fused[256 + (j-128)] = cb1[i1*128 + (j-128)];
    __syncthreads();

    double t = 0;
    {
      #pragma unroll 8
      for(int c=0;c<64;c++) t += (double)sm.p4.e[c]*(double)WfbT[(size_t)c*256 + j];
      t += (double)bfb[j];
    }
    double m = blk_sum_256(t, sm.p4.red) / 256.0;
    double d = t - m;
    double v = blk_sum_256(d*d, sm.p4.red) / 256.0;
    sm.p4.fused[j] = (float)(d / sqrt(v + 1e-5));
    __syncthreads();

    double o = 0;
    {
      #pragma unroll 8
      for(int i=0;i<384;i++) o += (double)sm.p4.fused[i]*(double)WfT[(size_t)i*256 + j];
      o += (double)bf[j];
    }
    m = blk_sum_256(o, sm.p4.red) / 256.0;
    d = o - m;
    v = blk_sum_256(d*d, sm.p4.red) / 256.0;
    double r = d / sqrt(v + 1e-5);
    if(r < 0) r = 0;
    table[(size_t)row*256 + j] = (float)r;
  }
}

// ========================= Kernel C: main ================================
// GEMM (x@Wl1^T) + LN + ReLU + scores + argmax + table gather.
// W tile via global_load_lds DMA; register prefetch of next-kk fragments.
__global__ __launch_bounds__(256) void hvq_main(
    const float* __restrict__ x, const float* __restrict__ Wl1T,
    const float* __restrict__ bl1, const float* __restrict__ H_all,
    const float* __restrict__ f_all, const int* __restrict__ idx1,
    const float* __restrict__ table, float* __restrict__ out){
  __shared__ float wsT[KB*256];   // [kk][n] 32KB; aliased as rT[256][32] after K-loop
  __shared__ float xs[TM*KB];     // [m][kk] 4KB
  __shared__ int kstar[TM];

  const int tid = threadIdx.x;
  const int tx = tid & 31, ty = tid >> 5;
  const int wave = tid >> 6;      // 0..3
  const int lane = tid & 63;
  const int b  = blockIdx.y;
  const int t0 = blockIdx.x * TM;
  const int i1 = idx1[b];

  float acc[4][8];
  #pragma unroll
  for(int j=0;j<4;j++)
    #pragma unroll
    for(int c=0;c<8;c++) acc[j][c] = 0.f;

  float bn[8];
  #pragma unroll
  for(int c=0;c<4;c++){ bn[c] = bl1[tx*4+c]; bn[c+4] = bl1[128 + tx*4 + c]; }

  // DMA: W: wave covers floats [wave*2048,+2048) of the 32KB tile (8x 1KB insts)
  //      x: wave covers rows 8w..8w+7; lane -> (row 8w+lane/8, chunk lane%8)
  const float* xsrc0 = x + ((size_t)(b*2048 + t0 + 8*wave + (lane>>3)))*1024 + (lane&7)*4;
  float* xdst = xs + wave*256;
  float* wdst = wsT + wave*2048;

  for(int kt=0; kt<1024/KB; kt++){
    const int k0 = kt*KB;
    const float* wsrc = Wl1T + (size_t)k0*256 + wave*2048 + lane*4;
    #pragma unroll
    for(int i=0;i<8;i++) async_copy16(wsrc + i*256, wdst + i*256);
    async_copy16(xsrc0 + k0, xdst);
    __syncthreads();

    float4 w0 = *(const float4*)&wsT[0*256 + tx*4];
    float4 w1 = *(const float4*)&wsT[0*256 + 128 + tx*4];
    float xc[4], xn[4];
    #pragma unroll
    for(int j=0;j<4;j++) xc[j] = xs[(ty*4+j)*KB + 0];

    #pragma unroll 8
    for(int kk=0;kk<KB;kk++){
      const int nk = (kk+1) & 31;
      const float4 nw0 = *(const float4*)&wsT[nk*256 + tx*4];
      const float4 nw1 = *(const float4*)&wsT[nk*256 + 128 + tx*4];
      #pragma unroll
      for(int j=0;j<4;j++) xn[j] = xs[(ty*4+j)*KB + nk];
      #pragma unroll
      for(int j=0;j<4;j++){
        const float xv = xc[j];
        acc[j][0] = fmaf(xv, w0.x, acc[j][0]);
        acc[j][1] = fmaf(xv, w0.y, acc[j][1]);
        acc[j][2] = fmaf(xv, w0.z, acc[j][2]);
        acc[j][3] = fmaf(xv, w0.w, acc[j][3]);
        acc[j][4] = fmaf(xv, w1.x, acc[j][4]);
        acc[j][5] = fmaf(xv, w1.y, acc[j][5]);
        acc[j][6] = fmaf(xv, w1.z, acc[j][6]);
        acc[j][7] = fmaf(xv, w1.w, acc[j][7]);
      }
      w0 = nw0; w1 = nw1;
      #pragma unroll
      for(int j=0;j<4;j++) xc[j] = xn[j];
    }
    __syncthreads();
  }

  // bias + LN(256) over row (reduce across 32 tx lanes) + ReLU -> rT
  float* rT = wsT;    // [n][m] = [256][32]
  #pragma unroll
  for(int j=0;j<4;j++){
    float s = 0.f;
    #pragma unroll
    for(int c=0;c<8;c++){ acc[j][c] += bn[c]; s += acc[j][c]; }
    #pragma unroll
    for(int off=16;off>=1;off>>=1) s += __shfl_xor(s, off);
    const float mean = s * (1.f/256.f);
    float d2 = 0.f;
    #pragma unroll
    for(int c=0;c<8;c++){ const float dv = acc[j][c]-mean; d2 += dv*dv; }
    #pragma unroll
    for(int off=16;off>=1;off>>=1) d2 += __shfl_xor(d2, off);
    const float inv = 1.f / sqrtf(d2*(1.f/256.f) + 1e-5f);
    const int m = ty*4 + j;
    #pragma unroll
    for(int c=0;c<8;c++){
      float r = (acc[j][c]-mean)*inv;
      r = fmaxf(r, 0.f);
      const int n = (c < 4) ? (tx*4 + c) : (128 + tx*4 + (c-4));
      rT[n*TM + m] = r;
    }
  }
  __syncthreads();

  // scores[m][k] = f_k + sum_n r[m][n]*H[i1][n][k]; argmax over k (32 lanes)
  const int k = tid & 31, mg = tid >> 5;
  const float* Hb = H_all + (size_t)i1*256*32 + k;
  const float fk = f_all[i1*32 + k];
  float s0=fk, s1=fk, s2=fk, s3=fk;
  #pragma unroll 4
  for(int n=0;n<256;n++){
    const float4 rm = *(const float4*)&rT[n*TM + mg*4];
    const float hv = Hb[(size_t)n*32];
    s0 = fmaf(rm.x, hv, s0);
    s1 = fmaf(rm.y, hv, s1);
    s2 = fmaf(rm.z, hv, s2);
    s3 = fmaf(rm.w, hv, s3);
  }
  float scv[4] = {s0, s1, s2, s3};
  #pragma unroll
  for(int j=0;j<4;j++){
    float best = scv[j]; int bi = k;
    #pragma unroll
    for(int off=16;off>=1;off>>=1){
      const float ov = __shfl_xor(best, off);
      const int   oi = __shfl_xor(bi, off);
      if(ov > best || (ov == best && oi < bi)){ best = ov; bi = oi; }
    }
    if(k == 0) kstar[mg*4 + j] = bi;
  }
  __syncthreads();

  float* ob = out + ((size_t)(b*2048 + t0))*256;
  for(int m=0;m<TM;m++){
    const float v = table[((size_t)(i1*32 + kstar[m]))*256 + tid];
    ob[(size_t)m*256 + tid] = v;
  }
}

// ---------------------------------------------------------------------------
extern "C" void kernel_launch(void* const* d_in, const int* in_sizes, int n_in,
                              void* d_out, int out_size, void* d_ws, size_t ws_size,
                              hipStream_t stream){
  const float* x   = (const float*)d_in[0];
  const float* Wg1 = (const float*)d_in[1];
  const float* bg1 = (const float*)d_in[2];
  const float* Wg2 = (const float*)d_in[3];
  const float* bg2 = (const float*)d_in[4];
  const float* Wl1 = (const float*)d_in[5];
  const float* bl1 = (const float*)d_in[6];
  const float* Wl2 = (const float*)d_in[7];
  const float* bl2 = (const float*)d_in[8];
  const float* Wp  = (const float*)d_in[9];
  const float* bp  = (const float*)d_in[10];
  const float* cb1 = (const float*)d_in[11];
  const float* Wtb = (const float*)d_in[12];
  const float* btb = (const float*)d_in[13];
  const float* Wfb = (const float*)d_in[14];
  const float* bfb = (const float*)d_in[15];
  const float* cb2 = (const float*)d_in[16];
  const float* Wf  = (const float*)d_in[17];
  const float* bf  = (const float*)d_in[18];
  float* out = (float*)d_out;

  char* w = (char*)d_ws;
  double* psum   = (double*)w; w += (size_t)16*16*1024*8;   // 2 MB
  double* psumsq = (double*)w; w += (size_t)16*16*1024*8;   // 2 MB
  float*  Wl1T   = (float*)w;  w += (size_t)1024*256*4;     // 1 MB
  float*  Wg1T   = (float*)w;  w += (size_t)1024*256*4;     // 1 MB
  float*  WfT    = (float*)w;  w += (size_t)384*256*4;
  float*  WfbT   = (float*)w;  w += (size_t)64*256*4;
  float*  Wg2T   = (float*)w;  w += (size_t)256*128*4;
  float*  WpT    = (float*)w;  w += (size_t)128*128*4;
  float*  H_all  = (float*)w;  w += (size_t)8*256*32*4;     // 256 KB
  float*  f_all  = (float*)w;  w += (size_t)8*32*4;
  float*  table  = (float*)w;  w += (size_t)256*256*4;      // 256 KB
  int*    idx1   = (int*)w;    w += 64;

  hvq_A<<<488, 256, 0, stream>>>(x, Wl1, Wg1, Wf, Wfb, Wg2, Wp, Wtb, Wl2, bl2, btb, cb2,
                                 psum, psumsq, Wl1T, Wg1T, WfT, WfbT, Wg2T, WpT,
                                 H_all, f_all);
  hvq_B<<<272, 256, 0, stream>>>(psum, psumsq, Wg1T, bg1, Wg2T, bg2, WpT, bp, cb1, cb2,
                                 WfbT, bfb, WfT, bf, idx1, table);
  hvq_main<<<dim3(64,16), 256, 0, stream>>>(x, Wl1T, bl1, H_all, f_all, idx1, table, out);
}

// Round 4
// 593.405 us; speedup vs baseline: 1.0695x; 1.0351x over previous
//
#include <hip/hip_runtime.h>
#include <math.h>

// ---------------------------------------------------------------------------
// HierarchicalVQEncoder forward.
//
// Eval mode: assign = hard one-hot (soft terms cancel), so out[b,t] depends
// ONLY on (idx1[b], idx2[b,t]) -> 8*32=256-row table + gather.
//
// idx2 = argmax_k [ r . H_all[i1][:,k] + f_all[i1][k] ],
//   r = relu(ln(x@Wl1^T+bl1))   (argmax invariant to positive scaling;
//   H,f fold Wl2,Wtb,btb,cb2; computed for ALL 8 i1 to break dependency)
//
// 3-kernel DAG:
//   A: x partial stats | tiled transposes (Wl1,Wg1,Wg2,Wp,Wf,Wfb) | fold H_all
//   B: global encoder -> idx1 (16 blocks) | output table (256 blocks)
//   C: main GEMM (TM=64 rows/block) + LN + scores + argmax + table gather
//
// Precision: big GEMM fp32, all folding math fp64.
// ---------------------------------------------------------------------------

#define TM 64
#define KB 32

typedef __attribute__((address_space(3))) void lds_void_t;
typedef const __attribute__((address_space(1))) void glb_void_t;

__device__ __forceinline__ void async_copy16(const float* g, float* l){
  __builtin_amdgcn_global_load_lds((glb_void_t*)g, (lds_void_t*)l, 16, 0, 0);
}

__device__ __forceinline__ double blk_sum_256(double v, double* red){
  const int tid = threadIdx.x;
  red[tid] = v; __syncthreads();
  #pragma unroll
  for(int s=128; s>0; s>>=1){ if(tid < s) red[tid] += red[tid+s]; __syncthreads(); }
  const double r = red[0]; __syncthreads();
  return r;
}

// ---- tiled 64x64 transpose helper (coalesced in AND out) ----------------
__device__ __forceinline__ void tile_transpose(
    const float* __restrict__ src, float* __restrict__ dst,
    int M, int N, int tile_id, float (*tile)[65]){
  const int tpr = N >> 6;
  const int r0 = (tile_id / tpr) << 6;
  const int c0 = (tile_id % tpr) << 6;
  const int t = threadIdx.x;
  {
    const int i = t >> 4, j4 = (t & 15) << 2;
    #pragma unroll
    for(int q=0;q<4;q++){
      const int row = i + (q<<4);
      const float4 v = *(const float4*)&src[(size_t)(r0+row)*N + c0 + j4];
      tile[row][j4+0]=v.x; tile[row][j4+1]=v.y; tile[row][j4+2]=v.z; tile[row][j4+3]=v.w;
    }
  }
  __syncthreads();
  {
    const int j = t >> 4, i4 = (t & 15) << 2;
    #pragma unroll
    for(int q=0;q<4;q++){
      const int col = j + (q<<4);
      float4 o;
      o.x = tile[i4+0][col]; o.y = tile[i4+1][col];
      o.z = tile[i4+2][col]; o.w = tile[i4+3][col];
      *(float4*)&dst[(size_t)(c0+col)*M + r0 + i4] = o;
    }
  }
}

// ========================= Kernel A (488 blocks) =========================
// [0,256)   p1 partial sums over T
// [256,320) Wl1 -> Wl1T (1024x256)
// [320,384) Wg1 -> Wg1T (1024x256)
// [384,408) Wf  -> WfT  (384x256)
// [408,412) Wfb -> WfbT (64x256)
// [412,420) Wg2 -> Wg2T (256x128)
// [420,424) Wp  -> WpT  (128x128)
// [424,488) fold H_all[8][256][32], f_all[8][32]
union SmemA {
  float tile[64][65];
  struct { double Wcs[64][33]; double bcs[64]; double cbd[32][64]; double nrm[32]; } fold;
};

__global__ __launch_bounds__(256) void hvq_A(
    const float* __restrict__ x,
    const float* __restrict__ Wl1, const float* __restrict__ Wg1,
    const float* __restrict__ Wf,  const float* __restrict__ Wfb,
    const float* __restrict__ Wg2, const float* __restrict__ Wp,
    const float* __restrict__ Wtb, const float* __restrict__ Wl2,
    const float* __restrict__ bl2, const float* __restrict__ btb,
    const float* __restrict__ cb2,
    double* __restrict__ psum, double* __restrict__ psumsq,
    float* __restrict__ Wl1T, float* __restrict__ Wg1T,
    float* __restrict__ WfT,  float* __restrict__ WfbT,
    float* __restrict__ Wg2T, float* __restrict__ WpT,
    float* __restrict__ H_all, float* __restrict__ f_all){
  __shared__ SmemA sm;
  const int blk = blockIdx.x;
  const int tid = threadIdx.x;

  if(blk < 256){
    // ---- p1 partial: per (b, t-chunk) sums/sumsq over 128 t ----
    const int tc = blk & 15, b = blk >> 4;
    const int d4 = tid * 4;
    const float* xp = x + ((size_t)(b*2048 + tc*128))*1024 + d4;
    double s0=0,s1=0,s2=0,s3=0, q0=0,q1=0,q2=0,q3=0;
    for(int t=0;t<128;t++){
      const float4 v = *(const float4*)&xp[(size_t)t*1024];
      s0 += v.x; q0 += (double)v.x*v.x;
      s1 += v.y; q1 += (double)v.y*v.y;
      s2 += v.z; q2 += (double)v.z*v.z;
      s3 += v.w; q3 += (double)v.w*v.w;
    }
    const size_t o = ((size_t)(b*16+tc))*1024 + d4;
    psum[o+0]=s0; psum[o+1]=s1; psum[o+2]=s2; psum[o+3]=s3;
    psumsq[o+0]=q0; psumsq[o+1]=q1; psumsq[o+2]=q2; psumsq[o+3]=q3;
  } else if(blk < 320){
    tile_transpose(Wl1, Wl1T, 256, 1024, blk-256, sm.tile);
  } else if(blk < 384){
    tile_transpose(Wg1, Wg1T, 256, 1024, blk-320, sm.tile);
  } else if(blk < 408){
    tile_transpose(Wf,  WfT,  256, 384,  blk-384, sm.tile);
  } else if(blk < 412){
    tile_transpose(Wfb, WfbT, 256, 64,   blk-408, sm.tile);
  } else if(blk < 420){
    tile_transpose(Wg2, Wg2T, 128, 256,  blk-412, sm.tile);
  } else if(blk < 424){
    tile_transpose(Wp,  WpT,  128, 128,  blk-420, sm.tile);
  } else {
    // ---- fold: H_all[i1][n][k], f_all[i1][k] (fp64) ----
    const int fb = blk - 424;
    const int ng = fb & 7;          // n-group (32 n each)
    const int i1 = fb >> 3;         // 0..7
    const int tn = tid & 31;
    const int kq = tid >> 5;        // 0..7
    const int n  = ng*32 + tn;

    if(tid < 32){
      const float* cr = cb2 + ((size_t)i1*32 + tid)*64;
      double n2 = 0;
      for(int c=0;c<64;c++){ const double v=(double)cr[c]; n2 += v*v; }
      sm.fold.nrm[tid] = fmax(sqrt(n2), 1e-12);
    }
    __syncthreads();
    for(int i=tid;i<2048;i+=256){
      const int k = i >> 6, c = i & 63;
      sm.fold.cbd[k][c] = (double)cb2[((size_t)i1*32+k)*64 + c] / sm.fold.nrm[k];
    }
    // Wc slice: Wc[c][n] = sum_j Wtb[c][j]*Wl2[j][n], c = kq*8..+7
    {
      double acc[8] = {0,0,0,0,0,0,0,0};
      const float* wt = Wtb + (size_t)(kq*8)*256;
      for(int j=0;j<256;j++){
        const double wl = (double)Wl2[(size_t)j*256 + n];   // coalesced across tn
        #pragma unroll
        for(int cc=0;cc<8;cc++) acc[cc] += (double)wt[cc*256 + j] * wl;
      }
      #pragma unroll
      for(int cc=0;cc<8;cc++) sm.fold.Wcs[kq*8+cc][tn] = acc[cc];
    }
    if(tid < 64){
      const float* wt = Wtb + (size_t)tid*256;
      double a = 0;
      for(int j=0;j<256;j++) a += (double)wt[j]*(double)bl2[j];
      sm.fold.bcs[tid] = a + (double)btb[tid];
    }
    __syncthreads();

    double su = 0;
    for(int c=0;c<64;c++) su += sm.fold.Wcs[c][tn];
    su /= 64.0;
    for(int t=0;t<4;t++){
      const int k = kq*4 + t;
      double acc=0, sk=0;
      for(int c=0;c<64;c++){ const double cc = sm.fold.cbd[k][c]; acc += sm.fold.Wcs[c][tn]*cc; sk += cc; }
      H_all[((size_t)i1*256 + n)*32 + k] = (float)(acc - su*sk);
    }
    if(ng == 0 && tid < 32){
      const int k = tid;
      double acc=0, sk=0, sbc=0;
      for(int c=0;c<64;c++){ const double cc = sm.fold.cbd[k][c]; acc += sm.fold.bcs[c]*cc; sk += cc; sbc += sm.fold.bcs[c]; }
      f_all[i1*32 + k] = (float)(acc - (sbc/64.0)*sk);
    }
  }
}

// ========================= Kernel B (272 blocks) =========================
// [0,16)   p2: stats final + global encoder -> idx1[b]
// [16,272) p4: output table row (i1,k2)
union SmemB {
  struct { float gin[1024]; float sa[256]; float sb[128]; float sh[128];
           double red[256]; double lg[8]; int i1s; } p2;
  struct { float e[64]; float fused[384]; double red[256]; } p4;
};

__global__ __launch_bounds__(256) void hvq_B(
    const double* __restrict__ psum, const double* __restrict__ psumsq,
    const float* __restrict__ Wg1T, const float* __restrict__ bg1,
    const float* __restrict__ Wg2T, const float* __restrict__ bg2,
    const float* __restrict__ WpT,  const float* __restrict__ bp,
    const float* __restrict__ cb1,  const float* __restrict__ cb2,
    const float* __restrict__ WfbT, const float* __restrict__ bfb,
    const float* __restrict__ WfT,  const float* __restrict__ bf,
    int* __restrict__ idx1_g, float* __restrict__ table){
  __shared__ SmemB sm;
  const int tid = threadIdx.x;

  if(blockIdx.x < 16){
    const int b = blockIdx.x;
    // g_in = mean + std (ddof=1), fp64
    for(int i=tid;i<1024;i+=256){
      double s=0, ss=0;
      for(int tc=0;tc<16;tc++){
        const size_t o = ((size_t)(b*16+tc))*1024 + i;
        s += psum[o]; ss += psumsq[o];
      }
      const double mean = s / 2048.0;
      double var = (ss - s*mean) / 2047.0;
      if(var < 0) var = 0;
      sm.p2.gin[i] = (float)(mean + sqrt(var));
    }
    __syncthreads();

    // z = g_in @ Wg1^T + bg1  (coalesced via Wg1T)
    double z = 0;
    {
      #pragma unroll 8
      for(int k=0;k<1024;k++) z += (double)sm.p2.gin[k] * (double)Wg1T[(size_t)k*256 + tid];
      z += (double)bg1[tid];
    }
    const double mz = blk_sum_256(z, sm.p2.red) / 256.0;
    const double dz = z - mz;
    const double vz = blk_sum_256(dz*dz, sm.p2.red) / 256.0;
    double a = dz / sqrt(vz + 1e-5);
    if(a < 0) a = 0;
    sm.p2.sa[tid] = (float)a;
    __syncthreads();

    if(tid < 128){
      double g = 0;
      #pragma unroll 8
      for(int i=0;i<256;i++) g += (double)sm.p2.sa[i]*(double)Wg2T[(size_t)i*128 + tid];
      sm.p2.sb[tid] = (float)(g + (double)bg2[tid]);
    }
    __syncthreads();

    double h = 0;
    if(tid < 128){
      #pragma unroll 8
      for(int i=0;i<128;i++) h += (double)sm.p2.sb[i]*(double)WpT[(size_t)i*128 + tid];
      h += (double)bp[tid];
    }
    const double mh = blk_sum_256(tid<128 ? h : 0.0, sm.p2.red) / 128.0;
    const double dh = (tid<128) ? (h - mh) : 0.0;
    const double vh = blk_sum_256(dh*dh, sm.p2.red) / 128.0;
    const double h1 = dh / sqrt(vh + 1e-5);
    if(tid < 128) sm.p2.sh[tid] = (float)h1;
    const double nh2 = blk_sum_256(tid<128 ? h1*h1 : 0.0, sm.p2.red);
    const double normh = sqrt(nh2);
    __syncthreads();

    if(tid < 8){
      const float* cr = cb1 + tid*128;
      double dsum=0, n2=0;
      for(int i=0;i<128;i++){ const double c=(double)cr[i]; dsum += (double)sm.p2.sh[i]*c; n2 += c*c; }
      sm.p2.lg[tid] = dsum / (fmax(normh,1e-12) * fmax(sqrt(n2),1e-12));
    }
    __syncthreads();
    if(tid == 0){
      int bi=0; double bv=sm.p2.lg[0];
      for(int j=1;j<8;j++) if(sm.p2.lg[j] > bv){ bv=sm.p2.lg[j]; bi=j; }
      idx1_g[b] = bi;
    }
  } else {
    // ---- p4: table row for (i1,k2) ----
    const int row = blockIdx.x - 16;
    const int i1 = row >> 5, k2 = row & 31;
    const int j = tid;
    if(j < 64) sm.p4.e[j] = cb2[((size_t)i1*32 + k2)*64 + j];
    if(j >= 128 && j < 256) sm.p4.fused[256 + (j-128)] = cb1[i1*128 + (j-128)];
    __syncthreads();

    double t = 0;
    {
      #pragma unroll 8
      for(int c=0;c<64;c++) t += (double)sm.p4.e[c]*(double)WfbT[(size_t)c*256 + j];
      t += (double)bfb[j];
    }
    double m = blk_sum_256(t, sm.p4.red) / 256.0;
    double d = t - m;
    double v = blk_sum_256(d*d, sm.p4.red) / 256.0;
    sm.p4.fused[j] = (float)(d / sqrt(v + 1e-5));
    __syncthreads();

    double o = 0;
    {
      #pragma unroll 8
      for(int i=0;i<384;i++) o += (double)sm.p4.fused[i]*(double)WfT[(size_t)i*256 + j];
      o += (double)bf[j];
    }
    m = blk_sum_256(o, sm.p4.red) / 256.0;
    d = o - m;
    v = blk_sum_256(d*d, sm.p4.red) / 256.0;
    double r = d / sqrt(v + 1e-5);
    if(r < 0) r = 0;
    table[(size_t)row*256 + j] = (float)r;
  }
}

// ========================= Kernel C: main (TM=64) ========================
// GEMM (x@Wl1^T) + LN + ReLU + scores + argmax + table gather.
// 32KB W-tile feeds 64 rows (2x FMA per staged byte vs TM=32).
// LDS pool: [wsT 32KB][xs 8KB]; rT (stride 36, conflict-free) aliases pool.
__global__ __launch_bounds__(256) void hvq_main(
    const float* __restrict__ x, const float* __restrict__ Wl1T,
    const float* __restrict__ bl1, const float* __restrict__ H_all,
    const float* __restrict__ f_all, const int* __restrict__ idx1,
    const float* __restrict__ table, float* __restrict__ out){
  __shared__ float smem[KB*256 + TM*KB];   // 8192 + 2048 floats = 40KB
  __shared__ int kstar[TM];
  float* wsT = smem;            // [kk][256]
  float* xs  = smem + KB*256;   // [m][kk]
  float* rT  = smem;            // [n][36] stride-padded, 9216 floats (36KB)

  const int tid = threadIdx.x;
  const int tx = tid & 31, ty = tid >> 5;
  const int wave = tid >> 6;    // 0..3
  const int lane = tid & 63;
  const int b  = blockIdx.y;
  const int t0 = blockIdx.x * TM;
  const int i1 = idx1[b];

  float acc[8][8];
  #pragma unroll
  for(int j=0;j<8;j++)
    #pragma unroll
    for(int c=0;c<8;c++) acc[j][c] = 0.f;

  float bn[8];
  #pragma unroll
  for(int c=0;c<4;c++){ bn[c] = bl1[tx*4+c]; bn[c+4] = bl1[128 + tx*4 + c]; }

  // DMA: W: wave covers floats [wave*2048,+2048) of the 32KB tile (8x 1KB insts)
  //      x: 2 insts/wave; inst i: row = i*32 + wave*8 + lane/8, chunk lane%8
  const float* xsrc0 = x + ((size_t)(b*2048 + t0 + wave*8 + (lane>>3)))*1024 + (lane&7)*4;
  const float* xsrc1 = xsrc0 + (size_t)32*1024;
  float* xdst0 = xs + wave*8*KB;
  float* xdst1 = xdst0 + 32*KB;
  float* wdst = wsT + wave*2048;

  for(int kt=0; kt<1024/KB; kt++){
    const int k0 = kt*KB;
    const float* wsrc = Wl1T + (size_t)k0*256 + wave*2048 + lane*4;
    #pragma unroll
    for(int i=0;i<8;i++) async_copy16(wsrc + i*256, wdst + i*256);
    async_copy16(xsrc0 + k0, xdst0);
    async_copy16(xsrc1 + k0, xdst1);
    __syncthreads();

    #pragma unroll
    for(int kg=0; kg<KB/4; kg++){
      float4 xv[8];
      #pragma unroll
      for(int j=0;j<8;j++) xv[j] = *(const float4*)&xs[(ty*8+j)*KB + kg*4];
      #pragma unroll
      for(int t=0;t<4;t++){
        const int kk = kg*4 + t;
        const float4 w0 = *(const float4*)&wsT[kk*256 + tx*4];
        const float4 w1 = *(const float4*)&wsT[kk*256 + 128 + tx*4];
        #pragma unroll
        for(int j=0;j<8;j++){
          const float xvj = (&xv[j].x)[t];
          acc[j][0] = fmaf(xvj, w0.x, acc[j][0]);
          acc[j][1] = fmaf(xvj, w0.y, acc[j][1]);
          acc[j][2] = fmaf(xvj, w0.z, acc[j][2]);
          acc[j][3] = fmaf(xvj, w0.w, acc[j][3]);
          acc[j][4] = fmaf(xvj, w1.x, acc[j][4]);
          acc[j][5] = fmaf(xvj, w1.y, acc[j][5]);
          acc[j][6] = fmaf(xvj, w1.z, acc[j][6]);
          acc[j][7] = fmaf(xvj, w1.w, acc[j][7]);
        }
      }
    }
    __syncthreads();
  }

  // bias + LN(256) per row (reduce across 32 tx lanes) + ReLU, in registers
  #pragma unroll
  for(int j=0;j<8;j++){
    float s = 0.f;
    #pragma unroll
    for(int c=0;c<8;c++){ acc[j][c] += bn[c]; s += acc[j][c]; }
    #pragma unroll
    for(int off=16;off>=1;off>>=1) s += __shfl_xor(s, off);
    const float mean = s * (1.f/256.f);
    float d2 = 0.f;
    #pragma unroll
    for(int c=0;c<8;c++){ const float dv = acc[j][c]-mean; d2 += dv*dv; }
    #pragma unroll
    for(int off=16;off>=1;off>>=1) d2 += __shfl_xor(d2, off);
    const float inv = 1.f / sqrtf(d2*(1.f/256.f) + 1e-5f);
    #pragma unroll
    for(int c=0;c<8;c++) acc[j][c] = fmaxf((acc[j][c]-mean)*inv, 0.f);
  }

  // scores in two 32-row halves (rT = 32 rows x 256 n, stride 36)
  const int k = tid & 31, mg = tid >> 5;
  const float* Hb = H_all + (size_t)i1*256*32 + k;
  const float fk = f_all[i1*32 + k];
  const int half_owner = ty >> 2;        // which half this thread's rows are in
  const int mm_base = (ty & 3)*8;

  for(int h=0; h<2; h++){
    __syncthreads();                     // prior phase reads done / K-loop done
    if(half_owner == h){
      #pragma unroll
      for(int j=0;j<8;j++){
        #pragma unroll
        for(int c=0;c<8;c++){
          const int n = (c < 4) ? (tx*4 + c) : (128 + tx*4 + (c-4));
          rT[n*36 + mm_base + j] = acc[j][c];
        }
      }
    }
    __syncthreads();

    float s0=fk, s1=fk, s2=fk, s3=fk;
    #pragma unroll 4
    for(int n=0;n<256;n++){
      const float4 rm = *(const float4*)&rT[n*36 + mg*4];
      const float hv = Hb[(size_t)n*32];
      s0 = fmaf(rm.x, hv, s0);
      s1 = fmaf(rm.y, hv, s1);
      s2 = fmaf(rm.z, hv, s2);
      s3 = fmaf(rm.w, hv, s3);
    }
    float scv[4] = {s0, s1, s2, s3};
    #pragma unroll
    for(int j=0;j<4;j++){
      float best = scv[j]; int bi = k;
      #pragma unroll
      for(int off=16;off>=1;off>>=1){
        const float ov = __shfl_xor(best, off);
        const int   oi = __shfl_xor(bi, off);
        if(ov > best || (ov == best && oi < bi)){ best = ov; bi = oi; }
      }
      if(k == 0) kstar[h*32 + mg*4 + j] = bi;
    }
  }
  __syncthreads();

  float* ob = out + ((size_t)(b*2048 + t0))*256;
  for(int m=0;m<TM;m++){
    const float v = table[((size_t)(i1*32 + kstar[m]))*256 + tid];
    ob[(size_t)m*256 + tid] = v;
  }
}

// ---------------------------------------------------------------------------
extern "C" void kernel_launch(void* const* d_in, const int* in_sizes, int n_in,
                              void* d_out, int out_size, void* d_ws, size_t ws_size,
                              hipStream_t stream){
  const float* x   = (const float*)d_in[0];
  const float* Wg1 = (const float*)d_in[1];
  const float* bg1 = (const float*)d_in[2];
  const float* Wg2 = (const float*)d_in[3];
  const float* bg2 = (const float*)d_in[4];
  const float* Wl1 = (const float*)d_in[5];
  const float* bl1 = (const float*)d_in[6];
  const float* Wl2 = (const float*)d_in[7];
  const float* bl2 = (const float*)d_in[8];
  const float* Wp  = (const float*)d_in[9];
  const float* bp  = (const float*)d_in[10];
  const float* cb1 = (const float*)d_in[11];
  const float* Wtb = (const float*)d_in[12];
  const float* btb = (const float*)d_in[13];
  const float* Wfb = (const float*)d_in[14];
  const float* bfb = (const float*)d_in[15];
  const float* cb2 = (const float*)d_in[16];
  const float* Wf  = (const float*)d_in[17];
  const float* bf  = (const float*)d_in[18];
  float* out = (float*)d_out;

  char* w = (char*)d_ws;
  double* psum   = (double*)w; w += (size_t)16*16*1024*8;   // 2 MB
  double* psumsq = (double*)w; w += (size_t)16*16*1024*8;   // 2 MB
  float*  Wl1T   = (float*)w;  w += (size_t)1024*256*4;     // 1 MB
  float*  Wg1T   = (float*)w;  w += (size_t)1024*256*4;     // 1 MB
  float*  WfT    = (float*)w;  w += (size_t)384*256*4;
  float*  WfbT   = (float*)w;  w += (size_t)64*256*4;
  float*  Wg2T   = (float*)w;  w += (size_t)256*128*4;
  float*  WpT    = (float*)w;  w += (size_t)128*128*4;
  float*  H_all  = (float*)w;  w += (size_t)8*256*32*4;     // 256 KB
  float*  f_all  = (float*)w;  w += (size_t)8*32*4;
  float*  table  = (float*)w;  w += (size_t)256*256*4;      // 256 KB
  int*    idx1   = (int*)w;    w += 64;

  hvq_A<<<488, 256, 0, stream>>>(x, Wl1, Wg1, Wf, Wfb, Wg2, Wp, Wtb, Wl2, bl2, btb, cb2,
                                 psum, psumsq, Wl1T, Wg1T, WfT, WfbT, Wg2T, WpT,
                                 H_all, f_all);
  hvq_B<<<272, 256, 0, stream>>>(psum, psumsq, Wg1T, bg1, Wg2T, bg2, WpT, bp, cb1, cb2,
                                 WfbT, bfb, WfT, bf, idx1, table);
  hvq_main<<<dim3(32,16), 256, 0, stream>>>(x, Wl1T, bl1, H_all, f_all, idx1, table, out);
}